// Round 1
// baseline (567.775 us; speedup 1.0000x reference)
//
#include <hip/hip_runtime.h>

// Convert2Image: out[b,h,w,:] = lstm[b, slic[b,h,w]-1, :]
// B=4, S=256, C=128, H=W=512. fp32 in/out.
// Pure streaming gather: 512 MiB written, ~4.5 MiB effectively read.
// One thread = one float4 (16 B) of output. All dims are powers of two:
//   C/4 = 32 = 2^5, H*W = 2^18, S = 2^8  -> shifts/ands only.

constexpr int C4      = 32;      // C/4 float4 per pixel
constexpr int LOG_C4  = 5;
constexpr int LOG_HW  = 18;      // H*W = 262144
constexpr int LOG_S   = 8;       // S = 256

__global__ __launch_bounds__(256)
void convert2image_kernel(const float4* __restrict__ lstm,  // [B*S*C4]
                          const int*    __restrict__ slic,  // [B*H*W], 1-based
                          float4*       __restrict__ out,   // [B*H*W*C4]
                          int n4)
{
    int i = blockIdx.x * 256 + threadIdx.x;
    if (i >= n4) return;

    int c4  = i & (C4 - 1);          // float4 index within channel row
    int pix = i >> LOG_C4;           // linear pixel over B*H*W
    int b   = pix >> LOG_HW;         // batch
    int seg = slic[pix] - 1;         // 0-based segment id, in [0, S)

    // source row: lstm[b, seg, :] -> float4 index ((b<<LOG_S)+seg)*C4 + c4
    out[i] = lstm[(((b << LOG_S) + seg) << LOG_C4) + c4];
}

extern "C" void kernel_launch(void* const* d_in, const int* in_sizes, int n_in,
                              void* d_out, int out_size, void* d_ws, size_t ws_size,
                              hipStream_t stream) {
    const float4* lstm = (const float4*)d_in[0];   // graph_lstm_output [4,256,128] f32
    const int*    slic = (const int*)d_in[1];      // slic_output [4,512,512] i32
    float4*       out  = (float4*)d_out;           // [4,512,512,128] f32

    int n4 = out_size / 4;                         // 33,554,432 float4 elements
    int blocks = (n4 + 255) / 256;                 // 131,072 blocks, no tail
    convert2image_kernel<<<blocks, 256, 0, stream>>>(lstm, slic, out, n4);
}